// Round 5
// baseline (529.311 us; speedup 1.0000x reference)
//
#include <hip/hip_runtime.h>
#include <stdint.h>

// DecLayer: ProteinMPNN-style decoder layer. B=4,N=2048,K=48,H=IN=128.
// Device I/O float32; internals bf16 MFMA + f32 accum.
// R5: software-pipelined hE staging (register prefetch), LN3 residual from
// staged bf16 tile (no hE re-read), bf16 gather table in d_ws.

typedef __attribute__((ext_vector_type(8))) short bf16x8;
typedef __attribute__((ext_vector_type(4))) float f32x4;

#define MFMA16(a,b,c) __builtin_amdgcn_mfma_f32_16x16x32_bf16((a),(b),(c),0,0,0)

__device__ __forceinline__ float bf2f(uint16_t u){
  union { uint32_t i; float f; } v; v.i = ((uint32_t)u) << 16; return v.f;
}
__device__ __forceinline__ uint16_t f2bf(float f){
  union { float f; uint32_t i; } v; v.f = f;
  uint32_t u = v.i;
  u += 0x7fffu + ((u >> 16) & 1u);   // RNE
  return (uint16_t)(u >> 16);
}
__device__ __forceinline__ uint32_t pk2(float lo, float hi){
  return (uint32_t)f2bf(lo) | ((uint32_t)f2bf(hi) << 16);
}
__device__ __forceinline__ uint4 pk8(const float4& a, const float4& b){
  uint4 v; v.x=pk2(a.x,a.y); v.y=pk2(a.z,a.w); v.z=pk2(b.x,b.y); v.w=pk2(b.z,b.w);
  return v;
}
__device__ __forceinline__ float geluf(float x){
  float x2 = x*x;
  float u = 0.7978845608028654f * x * fmaf(0.044715f, x2, 1.0f);
  float t = fminf(fmaxf(2.8853900817779268f * u, -80.f), 80.f);
  float e = __builtin_amdgcn_exp2f(t);
  float r = __builtin_amdgcn_rcpf(1.0f + e);
  return fmaf(-x, r, x);
}
__device__ __forceinline__ bf16x8 wfragf(const float* __restrict__ W, int ncols,
                                         int k0, int col, int g){
  const float* p = W + (size_t)(k0 + g*8)*ncols + col;
  bf16x8 f;
#pragma unroll
  for (int j=0;j<8;j++) f[j] = (short)f2bf(p[j*ncols]);
  return f;
}
__device__ __forceinline__ bf16x8 afrag(const uint4* tile, int row, int s, int g){
  return *(const bf16x8*)&tile[row*16 + ((4*s + g) ^ (row & 7))];
}
__device__ __forceinline__ void st_m(uint4* tile, int row, int col, uint16_t val){
  int chunk = col >> 3;
  ((uint16_t*)&tile[row*16 + (chunk ^ (row & 7))])[col & 7] = val;
}

// ---------------- kernel 1: edge-message MLP + masked sum + LN1 ----------------
__global__ __launch_bounds__(512, 4) void k_node(
  const float* __restrict__ hV, const float* __restrict__ hE,
  const float* __restrict__ mAtt,
  const float* __restrict__ W1, const float* __restrict__ B1,
  const float* __restrict__ W2, const float* __restrict__ B2,
  const float* __restrict__ W3, const float* __restrict__ B3,
  const float* __restrict__ LG1, const float* __restrict__ LB1,
  float* __restrict__ x1f, uint16_t* __restrict__ x1b)
{
  __shared__ uint4 Ab[2][48*16];   // staged hE; layer2 output overwrites
  __shared__ uint4 Cb[2][48*16];   // lm1
  __shared__ uint4 hvb[2][16];
  __shared__ float maskb[2][48];
  __shared__ float dhb[2][128];

  const int tid = threadIdx.x;
  const int w = tid >> 6, lane = tid & 63, g = lane >> 4, l15 = lane & 15;
  const int col = w*16 + l15;

  bf16x8 W1f[8], W2f[4], W3f[4];
#pragma unroll
  for (int s=0;s<8;s++) W1f[s] = wfragf(W1,128,32*s,col,g);
#pragma unroll
  for (int s=0;s<4;s++) W2f[s] = wfragf(W2,128,32*s,col,g);
#pragma unroll
  for (int s=0;s<4;s++) W3f[s] = wfragf(W3,128,32*s,col,g);
  const float b1c = B1[col], b2c = B2[col], b3c = B3[col];

  float4 sr[6], hva, hvc; float mk = 0.f;

#define NODE_LOAD(itv) do{                                                     \
    const int m0 = blockIdx.x*16 + 2*(itv), m1 = m0 + 1;                       \
    _Pragma("unroll")                                                          \
    for (int q=0;q<3;q++){                                                     \
      int c = tid + 512*q; int cc = (c<768)? c : c-768;                        \
      const float* p = hE + (size_t)((c<768)? m0 : m1)*6144 + (size_t)cc*8;    \
      sr[2*q] = *(const float4*)p; sr[2*q+1] = *(const float4*)(p+4); }        \
    if (tid < 32){                                                             \
      const float* p = hV + (size_t)((tid<16)? m0 : m1)*128 + (tid&15)*8;      \
      hva = *(const float4*)p; hvc = *(const float4*)(p+4); }                  \
    if (tid >= 64 && tid < 160){ int k = tid-64;                               \
      mk = mAtt[(size_t)((k<48)? m0 : m1)*48 + ((k<48)? k : k-48)]; }          \
  }while(0)

  NODE_LOAD(0);

  for (int it=0; it<8; ++it){
    const int n0 = blockIdx.x*16 + 2*it, n1 = n0 + 1;
    // ---------- stage (regs -> LDS) ----------
#pragma unroll
    for (int q=0;q<3;q++){
      int c = tid + 512*q; int cc = (c<768)? c : c-768;
      uint4* dst = (c<768)? Ab[0] : Ab[1];
      int row = cc>>4, cir = cc&15;
      dst[row*16 + (cir ^ (row&7))] = pk8(sr[2*q], sr[2*q+1]);
    }
    if (tid < 32) hvb[tid>>4][tid&15] = pk8(hva, hvc);
    if (tid >= 64 && tid < 160){ int k = tid-64; maskb[k>=48][(k<48)? k : k-48] = mk; }
    __syncthreads();
    if (it < 7) NODE_LOAD(it+1);    // prefetch next pair under compute
    // ---------- layer 1 ----------
    f32x4 ahv[2] = {{0,0,0,0},{0,0,0,0}};
#pragma unroll
    for (int n=0;n<2;n++)
#pragma unroll
      for (int s=0;s<4;s++) ahv[n] = MFMA16(*(const bf16x8*)&hvb[n][4*s+g], W1f[s], ahv[n]);
#pragma unroll
    for (int n=0;n<2;n++)
#pragma unroll
      for (int t=0;t<3;t++){
        f32x4 acc = ahv[n];
        int row = 16*t + l15;
#pragma unroll
        for (int s=0;s<4;s++) acc = MFMA16(afrag(Ab[n],row,s,g), W1f[4+s], acc);
#pragma unroll
        for (int r=0;r<4;r++) st_m(Cb[n], 16*t+4*g+r, col, f2bf(geluf(acc[r]+b1c)));
      }
    __syncthreads();
    // ---------- layer 2 (into Ab) ----------
#pragma unroll
    for (int n=0;n<2;n++)
#pragma unroll
      for (int t=0;t<3;t++){
        f32x4 acc = {0,0,0,0};
        int row = 16*t + l15;
#pragma unroll
        for (int s=0;s<4;s++) acc = MFMA16(afrag(Cb[n],row,s,g), W2f[s], acc);
#pragma unroll
        for (int r=0;r<4;r++) st_m(Ab[n], 16*t+4*g+r, col, f2bf(geluf(acc[r]+b2c)));
      }
    __syncthreads();
    // ---------- layer 3 + masked sum ----------
    float pp[2] = {0.f, 0.f};
#pragma unroll
    for (int n=0;n<2;n++)
#pragma unroll
      for (int t=0;t<3;t++){
        f32x4 acc = {0,0,0,0};
        int row = 16*t + l15;
#pragma unroll
        for (int s=0;s<4;s++) acc = MFMA16(afrag(Ab[n],row,s,g), W3f[s], acc);
#pragma unroll
        for (int r=0;r<4;r++) pp[n] += maskb[n][16*t+4*g+r] * (acc[r] + b3c);
      }
#pragma unroll
    for (int n=0;n<2;n++){
      pp[n] += __shfl_xor(pp[n], 16);
      pp[n] += __shfl_xor(pp[n], 32);
    }
    if (lane < 16){ dhb[0][col] = pp[0]*(1.f/30.f); dhb[1][col] = pp[1]*(1.f/30.f); }
    __syncthreads();
    // ---------- LN1 (waves 0,1) ----------
    if (tid < 128){
      int n = tid >> 6;
      int node = n? n1 : n0;
      int c0 = 2*lane, c1 = c0+1;
      float2 hv2 = *(const float2*)(hV + (size_t)node*128 + c0);
      float xa = hv2.x + dhb[n][c0];
      float xc = hv2.y + dhb[n][c1];
      float s1 = xa + xc, s2 = xa*xa + xc*xc;
#pragma unroll
      for (int o=1;o<64;o<<=1){ s1 += __shfl_xor(s1,o); s2 += __shfl_xor(s2,o); }
      float mu = s1 * (1.0f/128.0f);
      float var = fmaxf(s2 * (1.0f/128.0f) - mu*mu, 0.f);
      float rstd = __builtin_amdgcn_rsqf(var + 1e-5f);
      float ya = (xa-mu)*rstd*LG1[c0] + LB1[c0];
      float yc = (xc-mu)*rstd*LG1[c1] + LB1[c1];
      float2 o2; o2.x = ya; o2.y = yc;
      ((float2*)x1f)[(size_t)node*64 + lane] = o2;
      ((uint32_t*)x1b)[(size_t)node*64 + lane] = pk2(ya, yc);
    }
    // no trailing barrier needed: next stage-write targets (Ab/hvb/maskb) were
    // last READ before the pre-LN1 barrier; dhb rewrite is 3 barriers away.
  }
#undef NODE_LOAD
}

// ---------------- kernel 2: fused FFN (128->512->128) + LN2 + mask_V ----------------
__global__ __launch_bounds__(512, 2) void k_ffn(
  const float* __restrict__ x1f, const uint16_t* __restrict__ x1b,
  const float* __restrict__ Win, const float* __restrict__ Bin,
  const float* __restrict__ Wout, const float* __restrict__ Bout,
  const float* __restrict__ LG2, const float* __restrict__ LB2,
  const float* __restrict__ maskV,
  float* __restrict__ outV, uint16_t* __restrict__ outVb)
{
  __shared__ uint4 lh[16*64];     // [16][512] bf16, swizzled
  __shared__ float xb[16*128];

  const int tid = threadIdx.x;
  const int w = tid>>6, lane = tid&63, g = lane>>4, l15 = lane&15;
  const int colo = w*16 + l15;

  bf16x8 WiF[4][4], WoF[16];
#pragma unroll
  for (int s=0;s<4;s++)
#pragma unroll
    for (int c=0;c<4;c++) WiF[s][c] = wfragf(Win,512,32*s, w*64 + c*16 + l15, g);
#pragma unroll
  for (int s=0;s<16;s++) WoF[s] = wfragf(Wout,128,32*s, colo, g);
  float binc[4];
#pragma unroll
  for (int c=0;c<4;c++) binc[c] = Bin[w*64 + c*16 + l15];
  const float boutc = Bout[colo];

  for (int it=0; it<2; ++it){
    const int node0 = (blockIdx.x*2 + it)*16;
    bf16x8 A[4];
#pragma unroll
    for (int s=0;s<4;s++) A[s] = *(const bf16x8*)(x1b + (size_t)(node0 + l15)*128 + 32*s + 8*g);
#pragma unroll
    for (int c=0;c<4;c++){
      f32x4 acc = {0,0,0,0};
#pragma unroll
      for (int s=0;s<4;s++) acc = MFMA16(A[s], WiF[s][c], acc);
      int colh = w*64 + c*16 + l15;
      int chunk = colh >> 3, within = colh & 7;
#pragma unroll
      for (int r=0;r<4;r++){
        int row = 4*g + r;
        ((uint16_t*)&lh[row*64 + (chunk ^ (row&7))])[within] = f2bf(geluf(acc[r] + binc[c]));
      }
    }
    __syncthreads();
    f32x4 acc = {0,0,0,0};
#pragma unroll
    for (int s=0;s<16;s++){
      bf16x8 a = *(const bf16x8*)&lh[l15*64 + ((4*s+g) ^ (l15 & 7))];
      acc = MFMA16(a, WoF[s], acc);
    }
#pragma unroll
    for (int r=0;r<4;r++){
      int row = 4*g + r;
      xb[row*128 + colo] = x1f[(size_t)(node0+row)*128 + colo] + acc[r] + boutc;
    }
    __syncthreads();
#pragma unroll
    for (int rr=0; rr<2; ++rr){
      int row = w + rr*8;
      int c0 = 2*lane, c1 = c0+1;
      float xa = xb[row*128 + c0], xc = xb[row*128 + c1];
      float s1 = xa + xc, s2 = xa*xa + xc*xc;
#pragma unroll
      for (int o=1;o<64;o<<=1){ s1 += __shfl_xor(s1,o); s2 += __shfl_xor(s2,o); }
      float mu = s1*(1.0f/128.0f);
      float var = fmaxf(s2*(1.0f/128.0f)-mu*mu, 0.f);
      float rstd = __builtin_amdgcn_rsqf(var + 1e-5f);
      float mv = maskV[node0 + row];
      float ya = ((xa-mu)*rstd*LG2[c0] + LB2[c0]) * mv;
      float yc = ((xc-mu)*rstd*LG2[c1] + LB2[c1]) * mv;
      float2 o2; o2.x = ya; o2.y = yc;
      ((float2*)outV)[(size_t)(node0+row)*64 + lane] = o2;
      if (outVb)
        ((uint32_t*)outVb)[(size_t)(node0+row)*64 + lane] = pk2(ya, yc);
    }
    __syncthreads();
  }
}

// ---------------- kernel 3: edge update MLP + LN3 ----------------
// Buffers: Ab = staged hE (bf16, survives to LN3 as residual);
//          Bb = gathered neighbors -> layer2 output; Cb = lm1 -> layer3 output.
template<bool BF16G>
__global__ __launch_bounds__(512, 4) void k_edge(
  const float* __restrict__ hE, const int* __restrict__ Eidx,
  const float* __restrict__ hV2f, const uint16_t* __restrict__ hV2b,
  const float* __restrict__ W11, const float* __restrict__ B11,
  const float* __restrict__ W12, const float* __restrict__ B12,
  const float* __restrict__ W13, const float* __restrict__ B13,
  const float* __restrict__ LG3, const float* __restrict__ LB3,
  float* __restrict__ outE)
{
  __shared__ uint4 Ab[2][48*16];
  __shared__ uint4 Bb[2][48*16];
  __shared__ uint4 Cb[2][48*16];
  __shared__ uint4 hvb[2][16];

  const int tid = threadIdx.x;
  const int w = tid>>6, lane = tid&63, g = lane>>4, l15 = lane&15;
  const int col = w*16 + l15;

  bf16x8 W11e[4], W11n[4], W12f[4], W13f[4];   // persistent: 64 VGPR
#pragma unroll
  for (int s=0;s<4;s++) W11e[s] = wfragf(W11,128,128+32*s,col,g);
#pragma unroll
  for (int s=0;s<4;s++) W11n[s] = wfragf(W11,128,256+32*s,col,g);
#pragma unroll
  for (int s=0;s<4;s++) W12f[s] = wfragf(W12,128,32*s,col,g);
#pragma unroll
  for (int s=0;s<4;s++) W13f[s] = wfragf(W13,128,32*s,col,g);
  const float b11c = B11[col], b12c = B12[col], b13c = B13[col];

  float4 sr[6]; int gi[3]; uint4 hvr; float4 hva, hvc;

#define EDGE_LOAD(itv) do{                                                     \
    const int m0 = blockIdx.x*16 + 2*(itv), m1 = m0 + 1;                       \
    _Pragma("unroll")                                                          \
    for (int q=0;q<3;q++){                                                     \
      int c = tid + 512*q; int cc = (c<768)? c : c-768;                        \
      const float* p = hE + (size_t)((c<768)? m0 : m1)*6144 + (size_t)cc*8;    \
      sr[2*q] = *(const float4*)p; sr[2*q+1] = *(const float4*)(p+4); }        \
    _Pragma("unroll")                                                          \
    for (int q=0;q<3;q++){                                                     \
      int c = tid + 512*q; int cc = (c<768)? c : c-768;                        \
      gi[q] = Eidx[(size_t)((c<768)? m0 : m1)*48 + (cc>>4)]; }                 \
    if (tid < 32){                                                             \
      int node = (tid<16)? m0 : m1;                                            \
      if (BF16G) hvr = *(const uint4*)(hV2b + (size_t)node*128 + (tid&15)*8);  \
      else { const float* p = hV2f + (size_t)node*128 + (tid&15)*8;            \
             hva = *(const float4*)p; hvc = *(const float4*)(p+4); } }         \
  }while(0)

  EDGE_LOAD(0);

  for (int it=0; it<8; ++it){
    const int n0 = blockIdx.x*16 + 2*it, n1 = n0 + 1;
    // ---------- gather loads first (L2-hot table), then stage writes ----------
    uint4 gq[3];
#pragma unroll
    for (int q=0;q<3;q++){
      int c = tid + 512*q; int cc = (c<768)? c : c-768;
      int node = (c<768)? n0 : n1;
      int bb = (node >> 11) << 11;
      if (BF16G){
        gq[q] = *(const uint4*)(hV2b + (size_t)(bb + gi[q])*128 + (cc&15)*8);
      } else {
        const float* p = hV2f + (size_t)(bb + gi[q])*128 + (cc&15)*8;
        gq[q] = pk8(*(const float4*)p, *(const float4*)(p+4));
      }
    }
#pragma unroll
    for (int q=0;q<3;q++){
      int c = tid + 512*q; int cc = (c<768)? c : c-768;
      uint4* dst = (c<768)? Ab[0] : Ab[1];
      int row = cc>>4, cir = cc&15;
      dst[row*16 + (cir ^ (row&7))] = pk8(sr[2*q], sr[2*q+1]);
    }
    if (tid < 32) hvb[tid>>4][tid&15] = BF16G ? hvr : pk8(hva, hvc);
#pragma unroll
    for (int q=0;q<3;q++){
      int c = tid + 512*q; int cc = (c<768)? c : c-768;
      uint4* dst = (c<768)? Bb[0] : Bb[1];
      int row = cc>>4, cir = cc&15;
      dst[row*16 + (cir ^ (row&7))] = gq[q];
    }
    __syncthreads();
    if (it < 7) EDGE_LOAD(it+1);     // prefetch next pair under compute
    bf16x8 Ws[4];                    // W11 self-part (L2-hot, transient)
#pragma unroll
    for (int s=0;s<4;s++) Ws[s] = wfragf(W11,128,32*s,col,g);
    // ---------- layer 1 -> Cb ----------
    f32x4 ahv[2] = {{0,0,0,0},{0,0,0,0}};
#pragma unroll
    for (int n=0;n<2;n++)
#pragma unroll
      for (int s=0;s<4;s++) ahv[n] = MFMA16(*(const bf16x8*)&hvb[n][4*s+g], Ws[s], ahv[n]);
#pragma unroll
    for (int n=0;n<2;n++)
#pragma unroll
      for (int t=0;t<3;t++){
        f32x4 acc = ahv[n];
        int row = 16*t + l15;
#pragma unroll
        for (int s=0;s<4;s++) acc = MFMA16(afrag(Ab[n],row,s,g), W11e[s], acc);
#pragma unroll
        for (int s=0;s<4;s++) acc = MFMA16(afrag(Bb[n],row,s,g), W11n[s], acc);
#pragma unroll
        for (int r=0;r<4;r++) st_m(Cb[n], 16*t+4*g+r, col, f2bf(geluf(acc[r]+b11c)));
      }
    __syncthreads();
    // ---------- layer 2 -> Bb ----------
#pragma unroll
    for (int n=0;n<2;n++)
#pragma unroll
      for (int t=0;t<3;t++){
        f32x4 acc = {0,0,0,0};
        int row = 16*t + l15;
#pragma unroll
        for (int s=0;s<4;s++) acc = MFMA16(afrag(Cb[n],row,s,g), W12f[s], acc);
#pragma unroll
        for (int r=0;r<4;r++) st_m(Bb[n], 16*t+4*g+r, col, f2bf(geluf(acc[r]+b12c)));
      }
    __syncthreads();
    // ---------- layer 3 -> Cb (bf16 msg) ----------
#pragma unroll
    for (int n=0;n<2;n++)
#pragma unroll
      for (int t=0;t<3;t++){
        f32x4 acc = {0,0,0,0};
        int row = 16*t + l15;
#pragma unroll
        for (int s=0;s<4;s++) acc = MFMA16(afrag(Bb[n],row,s,g), W13f[s], acc);
#pragma unroll
        for (int r=0;r<4;r++) st_m(Cb[n], 16*t+4*g+r, col, f2bf(acc[r]+b13c));
      }
    __syncthreads();
    // ---------- LN3: residual from Ab (bf16 staged hE), msg from Cb ----------
#pragma unroll
    for (int n=0;n<2;n++){
      int node = n? n1 : n0;
#pragma unroll
      for (int rr=0; rr<6; ++rr){
        int row = w + rr*8;
        int c0 = 2*lane;
        int ch = ((c0>>3) ^ (row&7));
        uint32_t pe = ((const uint32_t*)&Ab[n][row*16 + ch])[lane&3];
        uint32_t pv = ((const uint32_t*)&Cb[n][row*16 + ch])[lane&3];
        float xa = bf2f((uint16_t)(pe & 0xffff)) + bf2f((uint16_t)(pv & 0xffff));
        float xc = bf2f((uint16_t)(pe >> 16))    + bf2f((uint16_t)(pv >> 16));
        float s1 = xa + xc, s2 = xa*xa + xc*xc;
#pragma unroll
        for (int o=1;o<64;o<<=1){ s1 += __shfl_xor(s1,o); s2 += __shfl_xor(s2,o); }
        float mu = s1*(1.0f/128.0f);
        float var = fmaxf(s2*(1.0f/128.0f)-mu*mu, 0.f);
        float rstd = __builtin_amdgcn_rsqf(var+1e-5f);
        float ya = (xa-mu)*rstd*LG3[c0] + LB3[c0];
        float yc = (xc-mu)*rstd*LG3[c0+1] + LB3[c0+1];
        float2 o2; o2.x = ya; o2.y = yc;
        ((float2*)outE)[((size_t)node*48 + row)*64 + lane] = o2;
      }
    }
    __syncthreads();   // protect Ab/Cb from next iteration's stage writes
  }
#undef EDGE_LOAD
}

extern "C" void kernel_launch(void* const* d_in, const int* in_sizes, int n_in,
                              void* d_out, int out_size, void* d_ws, size_t ws_size,
                              hipStream_t stream){
  const float* hV   = (const float*)d_in[0];
  const float* hE   = (const float*)d_in[1];
  const float* mV   = (const float*)d_in[2];
  const int*   Eidx = (const int*)d_in[3];
  const float* mAtt = (const float*)d_in[4];
  const float* W1 = (const float*)d_in[5];  const float* B1 = (const float*)d_in[6];
  const float* W2 = (const float*)d_in[7];  const float* B2 = (const float*)d_in[8];
  const float* W3 = (const float*)d_in[9];  const float* B3 = (const float*)d_in[10];
  const float* W11 = (const float*)d_in[11]; const float* B11 = (const float*)d_in[12];
  const float* W12 = (const float*)d_in[13]; const float* B12 = (const float*)d_in[14];
  const float* W13 = (const float*)d_in[15]; const float* B13 = (const float*)d_in[16];
  const float* Win = (const float*)d_in[17]; const float* Bin = (const float*)d_in[18];
  const float* Wout= (const float*)d_in[19]; const float* Bout= (const float*)d_in[20];
  const float* LG1 = (const float*)d_in[21]; const float* LB1 = (const float*)d_in[22];
  const float* LG2 = (const float*)d_in[23]; const float* LB2 = (const float*)d_in[24];
  const float* LG3 = (const float*)d_in[25]; const float* LB3 = (const float*)d_in[26];

  float* outV = (float*)d_out;                     // [B*N*H] f32
  float* outE = outV + (size_t)1048576;            // [B*N*K*IN] f32
  float*    x1f = outE;                            // scratch, consumed by k_ffn
  uint16_t* x1b = (uint16_t*)(outE + (size_t)1048576);

  const bool bf16g = ws_size >= ((size_t)2<<20);
  uint16_t* outVb = bf16g ? (uint16_t*)d_ws : nullptr;   // 2 MB bf16 h_V table

  hipLaunchKernelGGL(k_node, dim3(512), dim3(512), 0, stream,
      hV, hE, mAtt, W1,B1, W2,B2, W3,B3, LG1,LB1, x1f, x1b);
  hipLaunchKernelGGL(k_ffn, dim3(256), dim3(512), 0, stream,
      x1f, x1b, Win,Bin, Wout,Bout, LG2,LB2, mV, outV, outVb);
  if (bf16g)
    hipLaunchKernelGGL((k_edge<true>), dim3(512), dim3(512), 0, stream,
        hE, Eidx, outV, outVb, W11,B11, W12,B12, W13,B13, LG3,LB3, outE);
  else
    hipLaunchKernelGGL((k_edge<false>), dim3(512), dim3(512), 0, stream,
        hE, Eidx, outV, nullptr, W11,B11, W12,B12, W13,B13, LG3,LB3, outE);
}

// Round 6
// 393.487 us; speedup vs baseline: 1.3452x; 1.3452x over previous
//
#include <hip/hip_runtime.h>
#include <stdint.h>

// DecLayer: ProteinMPNN-style decoder layer. B=4,N=2048,K=48,H=IN=128.
// Device I/O float32; internals bf16 MFMA + f32 accum.
// R6: R4 loop structure + amdgpu_waves_per_eu(4,4) to pin VGPR budget at 128
// so weight fragments stay register-resident (R4/R5 showed VGPR=64 => compiler
// rematerialized weights from global every iteration ~ +270MB FETCH).
// Keeps R5's LN3-residual-from-LDS and bf16 gather table.

typedef __attribute__((ext_vector_type(8))) short bf16x8;
typedef __attribute__((ext_vector_type(4))) float f32x4;

#define MFMA16(a,b,c) __builtin_amdgcn_mfma_f32_16x16x32_bf16((a),(b),(c),0,0,0)

__device__ __forceinline__ float bf2f(uint16_t u){
  union { uint32_t i; float f; } v; v.i = ((uint32_t)u) << 16; return v.f;
}
__device__ __forceinline__ uint16_t f2bf(float f){
  union { float f; uint32_t i; } v; v.f = f;
  uint32_t u = v.i;
  u += 0x7fffu + ((u >> 16) & 1u);   // RNE
  return (uint16_t)(u >> 16);
}
__device__ __forceinline__ uint32_t pk2(float lo, float hi){
  return (uint32_t)f2bf(lo) | ((uint32_t)f2bf(hi) << 16);
}
__device__ __forceinline__ uint4 pk8(const float4& a, const float4& b){
  uint4 v; v.x=pk2(a.x,a.y); v.y=pk2(a.z,a.w); v.z=pk2(b.x,b.y); v.w=pk2(b.z,b.w);
  return v;
}
__device__ __forceinline__ float geluf(float x){
  float x2 = x*x;
  float u = 0.7978845608028654f * x * fmaf(0.044715f, x2, 1.0f);
  float t = fminf(fmaxf(2.8853900817779268f * u, -80.f), 80.f);
  float e = __builtin_amdgcn_exp2f(t);
  float r = __builtin_amdgcn_rcpf(1.0f + e);
  return fmaf(-x, r, x);
}
__device__ __forceinline__ bf16x8 wfragf(const float* __restrict__ W, int ncols,
                                         int k0, int col, int g){
  const float* p = W + (size_t)(k0 + g*8)*ncols + col;
  bf16x8 f;
#pragma unroll
  for (int j=0;j<8;j++) f[j] = (short)f2bf(p[j*ncols]);
  return f;
}
__device__ __forceinline__ bf16x8 afrag(const uint4* tile, int row, int s, int g){
  return *(const bf16x8*)&tile[row*16 + ((4*s + g) ^ (row & 7))];
}
__device__ __forceinline__ void st_m(uint4* tile, int row, int col, uint16_t val){
  int chunk = col >> 3;
  ((uint16_t*)&tile[row*16 + (chunk ^ (row & 7))])[col & 7] = val;
}

// ---------------- kernel 1: edge-message MLP + masked sum + LN1 ----------------
__global__ __launch_bounds__(512) __attribute__((amdgpu_waves_per_eu(4,4)))
void k_node(
  const float* __restrict__ hV, const float* __restrict__ hE,
  const float* __restrict__ mAtt,
  const float* __restrict__ W1, const float* __restrict__ B1,
  const float* __restrict__ W2, const float* __restrict__ B2,
  const float* __restrict__ W3, const float* __restrict__ B3,
  const float* __restrict__ LG1, const float* __restrict__ LB1,
  float* __restrict__ x1f, uint16_t* __restrict__ x1b)
{
  __shared__ uint4 Ab[2][48*16];   // staged hE; layer2 output overwrites
  __shared__ uint4 Cb[2][48*16];   // lm1
  __shared__ uint4 hvb[2][16];
  __shared__ float maskb[2][48];
  __shared__ float dhb[2][128];

  const int tid = threadIdx.x;
  const int w = tid >> 6, lane = tid & 63, g = lane >> 4, l15 = lane & 15;
  const int col = w*16 + l15;

  bf16x8 W1f[8], W2f[4], W3f[4];   // 64 VGPR, persistent (waves_per_eu pins budget)
#pragma unroll
  for (int s=0;s<8;s++) W1f[s] = wfragf(W1,128,32*s,col,g);
#pragma unroll
  for (int s=0;s<4;s++) W2f[s] = wfragf(W2,128,32*s,col,g);
#pragma unroll
  for (int s=0;s<4;s++) W3f[s] = wfragf(W3,128,32*s,col,g);
  const float b1c = B1[col], b2c = B2[col], b3c = B3[col];

  for (int it=0; it<8; ++it){
    const int n0 = blockIdx.x*16 + 2*it, n1 = n0 + 1;
    // ---------- memory phase: all loads issue up front ----------
    float4 sr[6];
#pragma unroll
    for (int q=0;q<3;q++){
      int c = tid + 512*q;
      int cc = (c<768)? c : c-768;
      const float* p = hE + (size_t)((c<768)? n0 : n1)*6144 + (size_t)cc*8;
      sr[2*q]   = *(const float4*)p;
      sr[2*q+1] = *(const float4*)(p+4);
    }
    float4 hva, hvc; float mk = 0.f;
    if (tid < 32){
      const float* p = hV + (size_t)((tid<16)? n0 : n1)*128 + (tid&15)*8;
      hva = *(const float4*)p; hvc = *(const float4*)(p+4);
    }
    if (tid >= 64 && tid < 160){
      int k = tid - 64;
      mk = mAtt[(size_t)((k<48)? n0 : n1)*48 + ((k<48)? k : k-48)];
    }
#pragma unroll
    for (int q=0;q<3;q++){
      int c = tid + 512*q;
      int cc = (c<768)? c : c-768;
      uint4* dst = (c<768)? Ab[0] : Ab[1];
      int row = cc>>4, cir = cc&15;
      dst[row*16 + (cir ^ (row&7))] = pk8(sr[2*q], sr[2*q+1]);
    }
    if (tid < 32) hvb[tid>>4][tid&15] = pk8(hva, hvc);
    if (tid >= 64 && tid < 160){
      int k = tid - 64;
      maskb[k>=48][(k<48)? k : k-48] = mk;
    }
    __syncthreads();
    // ---------- layer 1 (+h_V part) ----------
    f32x4 ahv[2] = {{0,0,0,0},{0,0,0,0}};
#pragma unroll
    for (int n=0;n<2;n++)
#pragma unroll
      for (int s=0;s<4;s++) ahv[n] = MFMA16(*(const bf16x8*)&hvb[n][4*s+g], W1f[s], ahv[n]);
#pragma unroll
    for (int n=0;n<2;n++)
#pragma unroll
      for (int t=0;t<3;t++){
        f32x4 acc = ahv[n];
        int row = 16*t + l15;
#pragma unroll
        for (int s=0;s<4;s++) acc = MFMA16(afrag(Ab[n],row,s,g), W1f[4+s], acc);
#pragma unroll
        for (int r=0;r<4;r++) st_m(Cb[n], 16*t+4*g+r, col, f2bf(geluf(acc[r]+b1c)));
      }
    __syncthreads();
    // ---------- layer 2 (into Ab) ----------
#pragma unroll
    for (int n=0;n<2;n++)
#pragma unroll
      for (int t=0;t<3;t++){
        f32x4 acc = {0,0,0,0};
        int row = 16*t + l15;
#pragma unroll
        for (int s=0;s<4;s++) acc = MFMA16(afrag(Cb[n],row,s,g), W2f[s], acc);
#pragma unroll
        for (int r=0;r<4;r++) st_m(Ab[n], 16*t+4*g+r, col, f2bf(geluf(acc[r]+b2c)));
      }
    __syncthreads();
    // ---------- layer 3 + masked sum ----------
    float pp[2] = {0.f, 0.f};
#pragma unroll
    for (int n=0;n<2;n++)
#pragma unroll
      for (int t=0;t<3;t++){
        f32x4 acc = {0,0,0,0};
        int row = 16*t + l15;
#pragma unroll
        for (int s=0;s<4;s++) acc = MFMA16(afrag(Ab[n],row,s,g), W3f[s], acc);
#pragma unroll
        for (int r=0;r<4;r++) pp[n] += maskb[n][16*t+4*g+r] * (acc[r] + b3c);
      }
#pragma unroll
    for (int n=0;n<2;n++){
      pp[n] += __shfl_xor(pp[n], 16);
      pp[n] += __shfl_xor(pp[n], 32);
    }
    if (lane < 16){ dhb[0][col] = pp[0]*(1.f/30.f); dhb[1][col] = pp[1]*(1.f/30.f); }
    __syncthreads();
    // ---------- LN1 (waves 0,1) ----------
    if (tid < 128){
      int n = tid >> 6;
      int node = n? n1 : n0;
      int c0 = 2*lane, c1 = c0+1;
      float2 hv2 = *(const float2*)(hV + (size_t)node*128 + c0);
      float xa = hv2.x + dhb[n][c0];
      float xc = hv2.y + dhb[n][c1];
      float s1 = xa + xc, s2 = xa*xa + xc*xc;
#pragma unroll
      for (int o=1;o<64;o<<=1){ s1 += __shfl_xor(s1,o); s2 += __shfl_xor(s2,o); }
      float mu = s1 * (1.0f/128.0f);
      float var = fmaxf(s2 * (1.0f/128.0f) - mu*mu, 0.f);
      float rstd = __builtin_amdgcn_rsqf(var + 1e-5f);
      float ya = (xa-mu)*rstd*LG1[c0] + LB1[c0];
      float yc = (xc-mu)*rstd*LG1[c1] + LB1[c1];
      float2 o2; o2.x = ya; o2.y = yc;
      ((float2*)x1f)[(size_t)node*64 + lane] = o2;
      ((uint32_t*)x1b)[(size_t)node*64 + lane] = pk2(ya, yc);
    }
    __syncthreads();
  }
}

// ---------------- kernel 2: fused FFN (128->512->128) + LN2 + mask_V ----------------
__global__ __launch_bounds__(512) __attribute__((amdgpu_waves_per_eu(2,2)))
void k_ffn(
  const float* __restrict__ x1f, const uint16_t* __restrict__ x1b,
  const float* __restrict__ Win, const float* __restrict__ Bin,
  const float* __restrict__ Wout, const float* __restrict__ Bout,
  const float* __restrict__ LG2, const float* __restrict__ LB2,
  const float* __restrict__ maskV,
  float* __restrict__ outV, uint16_t* __restrict__ outVb)
{
  __shared__ uint4 lh[16*64];     // [16][512] bf16, swizzled
  __shared__ float xb[16*128];

  const int tid = threadIdx.x;
  const int w = tid>>6, lane = tid&63, g = lane>>4, l15 = lane&15;
  const int colo = w*16 + l15;

  bf16x8 WiF[4][4], WoF[16];      // 128 VGPR persistent
#pragma unroll
  for (int s=0;s<4;s++)
#pragma unroll
    for (int c=0;c<4;c++) WiF[s][c] = wfragf(Win,512,32*s, w*64 + c*16 + l15, g);
#pragma unroll
  for (int s=0;s<16;s++) WoF[s] = wfragf(Wout,128,32*s, colo, g);
  float binc[4];
#pragma unroll
  for (int c=0;c<4;c++) binc[c] = Bin[w*64 + c*16 + l15];
  const float boutc = Bout[colo];

  for (int it=0; it<2; ++it){
    const int node0 = (blockIdx.x*2 + it)*16;
    bf16x8 A[4];
#pragma unroll
    for (int s=0;s<4;s++) A[s] = *(const bf16x8*)(x1b + (size_t)(node0 + l15)*128 + 32*s + 8*g);
#pragma unroll
    for (int c=0;c<4;c++){
      f32x4 acc = {0,0,0,0};
#pragma unroll
      for (int s=0;s<4;s++) acc = MFMA16(A[s], WiF[s][c], acc);
      int colh = w*64 + c*16 + l15;
      int chunk = colh >> 3, within = colh & 7;
#pragma unroll
      for (int r=0;r<4;r++){
        int row = 4*g + r;
        ((uint16_t*)&lh[row*64 + (chunk ^ (row&7))])[within] = f2bf(geluf(acc[r] + binc[c]));
      }
    }
    __syncthreads();
    f32x4 acc = {0,0,0,0};
#pragma unroll
    for (int s=0;s<16;s++){
      bf16x8 a = *(const bf16x8*)&lh[l15*64 + ((4*s+g) ^ (l15 & 7))];
      acc = MFMA16(a, WoF[s], acc);
    }
#pragma unroll
    for (int r=0;r<4;r++){
      int row = 4*g + r;
      xb[row*128 + colo] = x1f[(size_t)(node0+row)*128 + colo] + acc[r] + boutc;
    }
    __syncthreads();
#pragma unroll
    for (int rr=0; rr<2; ++rr){
      int row = w + rr*8;
      int c0 = 2*lane, c1 = c0+1;
      float xa = xb[row*128 + c0], xc = xb[row*128 + c1];
      float s1 = xa + xc, s2 = xa*xa + xc*xc;
#pragma unroll
      for (int o=1;o<64;o<<=1){ s1 += __shfl_xor(s1,o); s2 += __shfl_xor(s2,o); }
      float mu = s1*(1.0f/128.0f);
      float var = fmaxf(s2*(1.0f/128.0f)-mu*mu, 0.f);
      float rstd = __builtin_amdgcn_rsqf(var + 1e-5f);
      float mv = maskV[node0 + row];
      float ya = ((xa-mu)*rstd*LG2[c0] + LB2[c0]) * mv;
      float yc = ((xc-mu)*rstd*LG2[c1] + LB2[c1]) * mv;
      float2 o2; o2.x = ya; o2.y = yc;
      ((float2*)outV)[(size_t)(node0+row)*64 + lane] = o2;
      if (outVb)
        ((uint32_t*)outVb)[(size_t)(node0+row)*64 + lane] = pk2(ya, yc);
    }
    __syncthreads();
  }
}

// ---------------- kernel 3: edge update MLP + LN3 ----------------
// Ab = staged hE (bf16, survives to LN3 residual); Bb = nbr -> l2 out;
// Cb = lm1 -> l3 out.
template<bool BF16G>
__global__ __launch_bounds__(512) __attribute__((amdgpu_waves_per_eu(4,4)))
void k_edge(
  const float* __restrict__ hE, const int* __restrict__ Eidx,
  const float* __restrict__ hV2f, const uint16_t* __restrict__ hV2b,
  const float* __restrict__ W11, const float* __restrict__ B11,
  const float* __restrict__ W12, const float* __restrict__ B12,
  const float* __restrict__ W13, const float* __restrict__ B13,
  const float* __restrict__ LG3, const float* __restrict__ LB3,
  float* __restrict__ outE)
{
  __shared__ uint4 Ab[2][48*16];
  __shared__ uint4 Bb[2][48*16];
  __shared__ uint4 Cb[2][48*16];
  __shared__ uint4 hvb[2][16];

  const int tid = threadIdx.x;
  const int w = tid>>6, lane = tid&63, g = lane>>4, l15 = lane&15;
  const int col = w*16 + l15;

  // ALL weights persistent: 20 frags = 80 VGPR (budget pinned to 128)
  bf16x8 Ws[4], W11e[4], W11n[4], W12f[4], W13f[4];
#pragma unroll
  for (int s=0;s<4;s++) Ws[s]   = wfragf(W11,128,     32*s,col,g);
#pragma unroll
  for (int s=0;s<4;s++) W11e[s] = wfragf(W11,128, 128+32*s,col,g);
#pragma unroll
  for (int s=0;s<4;s++) W11n[s] = wfragf(W11,128, 256+32*s,col,g);
#pragma unroll
  for (int s=0;s<4;s++) W12f[s] = wfragf(W12,128,     32*s,col,g);
#pragma unroll
  for (int s=0;s<4;s++) W13f[s] = wfragf(W13,128,     32*s,col,g);
  const float b11c = B11[col], b12c = B12[col], b13c = B13[col];

  for (int it=0; it<8; ++it){
    const int n0 = blockIdx.x*16 + 2*it, n1 = n0 + 1;
    // ---------- memory phase: sr + gi + hv issue, then gq, then LDS writes ----------
    float4 sr[6];
#pragma unroll
    for (int q=0;q<3;q++){
      int c = tid + 512*q; int cc = (c<768)? c : c-768;
      const float* p = hE + (size_t)((c<768)? n0 : n1)*6144 + (size_t)cc*8;
      sr[2*q]   = *(const float4*)p;
      sr[2*q+1] = *(const float4*)(p+4);
    }
    int gi[3];
#pragma unroll
    for (int q=0;q<3;q++){
      int c = tid + 512*q; int cc = (c<768)? c : c-768;
      gi[q] = Eidx[(size_t)((c<768)? n0 : n1)*48 + (cc>>4)];
    }
    uint4 hvr; float4 hva, hvc;
    if (tid < 32){
      int node = (tid<16)? n0 : n1;
      if (BF16G) hvr = *(const uint4*)(hV2b + (size_t)node*128 + (tid&15)*8);
      else { const float* p = hV2f + (size_t)node*128 + (tid&15)*8;
             hva = *(const float4*)p; hvc = *(const float4*)(p+4); }
    }
    uint4 gq[3];
#pragma unroll
    for (int q=0;q<3;q++){
      int c = tid + 512*q; int cc = (c<768)? c : c-768;
      int node = (c<768)? n0 : n1;
      int bb = (node >> 11) << 11;
      if (BF16G){
        gq[q] = *(const uint4*)(hV2b + (size_t)(bb + gi[q])*128 + (cc&15)*8);
      } else {
        const float* p = hV2f + (size_t)(bb + gi[q])*128 + (cc&15)*8;
        gq[q] = pk8(*(const float4*)p, *(const float4*)(p+4));
      }
    }
#pragma unroll
    for (int q=0;q<3;q++){
      int c = tid + 512*q; int cc = (c<768)? c : c-768;
      uint4* dst = (c<768)? Ab[0] : Ab[1];
      int row = cc>>4, cir = cc&15;
      dst[row*16 + (cir ^ (row&7))] = pk8(sr[2*q], sr[2*q+1]);
    }
    if (tid < 32) hvb[tid>>4][tid&15] = BF16G ? hvr : pk8(hva, hvc);
#pragma unroll
    for (int q=0;q<3;q++){
      int c = tid + 512*q; int cc = (c<768)? c : c-768;
      uint4* dst = (c<768)? Bb[0] : Bb[1];
      int row = cc>>4, cir = cc&15;
      dst[row*16 + (cir ^ (row&7))] = gq[q];
    }
    __syncthreads();
    // ---------- layer 1 -> Cb ----------
    f32x4 ahv[2] = {{0,0,0,0},{0,0,0,0}};
#pragma unroll
    for (int n=0;n<2;n++)
#pragma unroll
      for (int s=0;s<4;s++) ahv[n] = MFMA16(*(const bf16x8*)&hvb[n][4*s+g], Ws[s], ahv[n]);
#pragma unroll
    for (int n=0;n<2;n++)
#pragma unroll
      for (int t=0;t<3;t++){
        f32x4 acc = ahv[n];
        int row = 16*t + l15;
#pragma unroll
        for (int s=0;s<4;s++) acc = MFMA16(afrag(Ab[n],row,s,g), W11e[s], acc);
#pragma unroll
        for (int s=0;s<4;s++) acc = MFMA16(afrag(Bb[n],row,s,g), W11n[s], acc);
#pragma unroll
        for (int r=0;r<4;r++) st_m(Cb[n], 16*t+4*g+r, col, f2bf(geluf(acc[r]+b11c)));
      }
    __syncthreads();
    // ---------- layer 2 -> Bb ----------
#pragma unroll
    for (int n=0;n<2;n++)
#pragma unroll
      for (int t=0;t<3;t++){
        f32x4 acc = {0,0,0,0};
        int row = 16*t + l15;
#pragma unroll
        for (int s=0;s<4;s++) acc = MFMA16(afrag(Cb[n],row,s,g), W12f[s], acc);
#pragma unroll
        for (int r=0;r<4;r++) st_m(Bb[n], 16*t+4*g+r, col, f2bf(geluf(acc[r]+b12c)));
      }
    __syncthreads();
    // ---------- layer 3 -> Cb (bf16 msg) ----------
#pragma unroll
    for (int n=0;n<2;n++)
#pragma unroll
      for (int t=0;t<3;t++){
        f32x4 acc = {0,0,0,0};
        int row = 16*t + l15;
#pragma unroll
        for (int s=0;s<4;s++) acc = MFMA16(afrag(Bb[n],row,s,g), W13f[s], acc);
#pragma unroll
        for (int r=0;r<4;r++) st_m(Cb[n], 16*t+4*g+r, col, f2bf(acc[r]+b13c));
      }
    __syncthreads();
    // ---------- LN3: residual from Ab (staged bf16 hE) + msg from Cb ----------
#pragma unroll
    for (int n=0;n<2;n++){
      int node = n? n1 : n0;
#pragma unroll
      for (int rr=0; rr<6; ++rr){
        int row = w + rr*8;
        int c0 = 2*lane;
        int ch = ((c0>>3) ^ (row&7));
        uint32_t pe = ((const uint32_t*)&Ab[n][row*16 + ch])[lane&3];
        uint32_t pv = ((const uint32_t*)&Cb[n][row*16 + ch])[lane&3];
        float xa = bf2f((uint16_t)(pe & 0xffff)) + bf2f((uint16_t)(pv & 0xffff));
        float xc = bf2f((uint16_t)(pe >> 16))    + bf2f((uint16_t)(pv >> 16));
        float s1 = xa + xc, s2 = xa*xa + xc*xc;
#pragma unroll
        for (int o=1;o<64;o<<=1){ s1 += __shfl_xor(s1,o); s2 += __shfl_xor(s2,o); }
        float mu = s1*(1.0f/128.0f);
        float var = fmaxf(s2*(1.0f/128.0f)-mu*mu, 0.f);
        float rstd = __builtin_amdgcn_rsqf(var+1e-5f);
        float ya = (xa-mu)*rstd*LG3[c0] + LB3[c0];
        float yc = (xc-mu)*rstd*LG3[c0+1] + LB3[c0+1];
        float2 o2; o2.x = ya; o2.y = yc;
        ((float2*)outE)[((size_t)node*48 + row)*64 + lane] = o2;
      }
    }
    __syncthreads();   // protect Ab/Cb until next stage writes
  }
}

extern "C" void kernel_launch(void* const* d_in, const int* in_sizes, int n_in,
                              void* d_out, int out_size, void* d_ws, size_t ws_size,
                              hipStream_t stream){
  const float* hV   = (const float*)d_in[0];
  const float* hE   = (const float*)d_in[1];
  const float* mV   = (const float*)d_in[2];
  const int*   Eidx = (const int*)d_in[3];
  const float* mAtt = (const float*)d_in[4];
  const float* W1 = (const float*)d_in[5];  const float* B1 = (const float*)d_in[6];
  const float* W2 = (const float*)d_in[7];  const float* B2 = (const float*)d_in[8];
  const float* W3 = (const float*)d_in[9];  const float* B3 = (const float*)d_in[10];
  const float* W11 = (const float*)d_in[11]; const float* B11 = (const float*)d_in[12];
  const float* W12 = (const float*)d_in[13]; const float* B12 = (const float*)d_in[14];
  const float* W13 = (const float*)d_in[15]; const float* B13 = (const float*)d_in[16];
  const float* Win = (const float*)d_in[17]; const float* Bin = (const float*)d_in[18];
  const float* Wout= (const float*)d_in[19]; const float* Bout= (const float*)d_in[20];
  const float* LG1 = (const float*)d_in[21]; const float* LB1 = (const float*)d_in[22];
  const float* LG2 = (const float*)d_in[23]; const float* LB2 = (const float*)d_in[24];
  const float* LG3 = (const float*)d_in[25]; const float* LB3 = (const float*)d_in[26];

  float* outV = (float*)d_out;                     // [B*N*H] f32
  float* outE = outV + (size_t)1048576;            // [B*N*K*IN] f32
  float*    x1f = outE;                            // scratch, consumed by k_ffn
  uint16_t* x1b = (uint16_t*)(outE + (size_t)1048576);

  const bool bf16g = ws_size >= ((size_t)2<<20);
  uint16_t* outVb = bf16g ? (uint16_t*)d_ws : nullptr;   // 2 MB bf16 h_V table

  hipLaunchKernelGGL(k_node, dim3(512), dim3(512), 0, stream,
      hV, hE, mAtt, W1,B1, W2,B2, W3,B3, LG1,LB1, x1f, x1b);
  hipLaunchKernelGGL(k_ffn, dim3(256), dim3(512), 0, stream,
      x1f, x1b, Win,Bin, Wout,Bout, LG2,LB2, mV, outV, outVb);
  if (bf16g)
    hipLaunchKernelGGL((k_edge<true>), dim3(512), dim3(512), 0, stream,
        hE, Eidx, outV, outVb, W11,B11, W12,B12, W13,B13, LG3,LB3, outE);
  else
    hipLaunchKernelGGL((k_edge<false>), dim3(512), dim3(512), 0, stream,
        hE, Eidx, outV, nullptr, W11,B11, W12,B12, W13,B13, LG3,LB3, outE);
}